// Round 12
// baseline (230.506 us; speedup 1.0000x reference)
//
#include <hip/hip_runtime.h>

// ---------- types ----------
typedef __attribute__((ext_vector_type(8))) short bfrag8;   // 8 bf16 bit patterns (4 VGPRs)
typedef __attribute__((ext_vector_type(4))) short bfrag4;
typedef __attribute__((ext_vector_type(4))) float f32x4;

#if defined(__has_builtin)
#if __has_builtin(__builtin_amdgcn_cvt_pk_bf16_f32)
#define HAVE_PK_BF16 1
#endif
#endif

// ---------- bf16 helpers ----------
__device__ __forceinline__ float bf2f(unsigned short h){
  unsigned u = ((unsigned)h) << 16;
  return __builtin_bit_cast(float, u);
}
__device__ __forceinline__ unsigned short f2bf(float f){
  unsigned u = __builtin_bit_cast(unsigned, f);
  u = u + 0x7FFFu + ((u >> 16) & 1u);        // round-to-nearest-even
  return (unsigned short)(u >> 16);
}
// pack two f32 -> two bf16 in one dword (lo=a, hi=b); single instr on gfx950
__device__ __forceinline__ unsigned pk2bf(float a, float b){
#ifdef HAVE_PK_BF16
  typedef __attribute__((ext_vector_type(2))) __bf16 bf16x2_t;
  bf16x2_t r = __builtin_amdgcn_cvt_pk_bf16_f32(a, b);
  return __builtin_bit_cast(unsigned, r);
#else
  return (unsigned)f2bf(a) | ((unsigned)f2bf(b) << 16);
#endif
}
__device__ __forceinline__ bfrag8 gload8(const unsigned short* p){ // 16B-aligned global, bf16
  int4 v = *(const int4*)p;
  return __builtin_bit_cast(bfrag8, v);
}
__device__ __forceinline__ bfrag8 lds_load8(const unsigned short* p){ // 8B-aligned LDS
  bfrag4 lo = *(const bfrag4*)p;
  bfrag4 hi = *(const bfrag4*)(p + 4);
  bfrag8 r;
#pragma unroll
  for (int j = 0; j < 4; j++){ r[j] = lo[j]; r[4+j] = hi[j]; }
  return r;
}
__device__ __forceinline__ bfrag8 lds_load16B(const unsigned short* p){ // 16B-aligned LDS -> ds_read_b128
  int4 v = *(const int4*)p;
  return __builtin_bit_cast(bfrag8, v);
}
__device__ __forceinline__ f32x4 mfma16(bfrag8 a, bfrag8 b, f32x4 c){
  return __builtin_amdgcn_mfma_f32_16x16x32_bf16(a, b, c, 0, 0, 0);
}

// bf16 select from packed kv word (compile-time t after unroll).
// k lives in .x/.y, v lives in .z/.w of the int4.
__device__ __forceinline__ float bfk(int4 v, int t){
  unsigned w = (t < 2) ? (unsigned)v.x : (unsigned)v.y;
  unsigned h = (t & 1) ? (w >> 16) : (w & 0xFFFFu);
  return bf2f((unsigned short)h);
}
__device__ __forceinline__ float bfv(int4 v, int t){
  unsigned w = (t < 2) ? (unsigned)v.z : (unsigned)v.w;
  unsigned h = (t & 1) ? (w >> 16) : (w & 0xFFFFu);
  return bf2f((unsigned short)h);
}
__device__ __forceinline__ float bfq(uint2 v, int t){
  unsigned w = (t < 2) ? v.x : v.y;
  unsigned h = (t & 1) ? (w >> 16) : (w & 0xFFFFu);
  return bf2f((unsigned short)h);
}

// ---------- dtype-dispatched accessors (flag: 1 = tensor is f32) ----------
__device__ __forceinline__ float ldf(const void* p, size_t i, int f32){
  return f32 ? ((const float*)p)[i] : bf2f(((const unsigned short*)p)[i]);
}
__device__ __forceinline__ unsigned short ldbf(const void* p, size_t i, int f32){
  return f32 ? f2bf(((const float*)p)[i]) : ((const unsigned short*)p)[i];
}
__device__ __forceinline__ bfrag8 load8bf(const void* p, size_t base, int f32){
  if (f32){
    const float* f = (const float*)p + base;
    float4 x = *(const float4*)f;
    float4 y = *(const float4*)(f + 4);
    bfrag8 r;
    r[0]=(short)f2bf(x.x); r[1]=(short)f2bf(x.y); r[2]=(short)f2bf(x.z); r[3]=(short)f2bf(x.w);
    r[4]=(short)f2bf(y.x); r[5]=(short)f2bf(y.y); r[6]=(short)f2bf(y.z); r[7]=(short)f2bf(y.w);
    return r;
  }
  return gload8((const unsigned short*)p + base);
}

// ---------- reductions ----------
template<int CTRL>
__device__ __forceinline__ float dpp_add(float x){
  int xi = __builtin_bit_cast(int, x);
  int yi = __builtin_amdgcn_update_dpp(0, xi, CTRL, 0xF, 0xF, true);
  return x + __builtin_bit_cast(float, yi);
}
__device__ __forceinline__ float row16_sum(float x){
  x = dpp_add<0xB1>(x);    // quad_perm [1,0,3,2]  : + lane^1
  x = dpp_add<0x4E>(x);    // quad_perm [2,3,0,1]  : + lane^2
  x = dpp_add<0x141>(x);   // row_half_mirror      : + other quad
  x = dpp_add<0x140>(x);   // row_mirror           : + other 8-group
  return x;
}
__device__ __forceinline__ float xgrp_sum(float x){
  x += __shfl_xor(x, 16, 64);
  x += __shfl_xor(x, 32, 64);
  return x;
}
__device__ __forceinline__ int wave_isum(int x){
#pragma unroll
  for (int s = 1; s < 64; s <<= 1) x += __shfl_xor(x, s, 64);
  return x;
}

// ============================================================================
// Kernel 0a: dtype sniffing — parallel, one wave per tensor.
// ============================================================================
struct Ptrs { const void* p[21]; int n[21]; };
struct PrepPtrs { const void* w[6]; const void* wp; const void* b[11]; };

__global__ void detect_kernel(Ptrs ptrs, int* flags){
  const int lane = threadIdx.x & 63;
  const int wid = blockIdx.x * 4 + (threadIdx.x >> 6);
  if (wid >= 21) return;
  if (wid == 2){ if (lane == 0) flags[2] = 0; return; }   // neighbor_idx is int32

  const unsigned short* p = (const unsigned short*)ptrs.p[wid];
  int m = ptrs.n[wid]; if (m > 128) m = 128;
  int insane = 0, evenZero = 0, evenCnt = 0, oddNZ = 0, oddCnt = 0;
#pragma unroll
  for (int s = 0; s < 2; s++){
    int i = lane + s*64;
    if (i < m){
      unsigned short h = p[i];
      int e = (h >> 7) & 0xFF;
      bool z = (h & 0x7FFF) == 0;
      if (!z && (e == 0xFF || e < 90 || e > 140)) insane++;
      if (i & 1){ oddCnt++;  if (!z) oddNZ++; }
      else      { evenCnt++; if (z)  evenZero++; }
    }
  }
  insane = wave_isum(insane);
  evenZero = wave_isum(evenZero); evenCnt = wave_isum(evenCnt);
  oddNZ = wave_isum(oddNZ);       oddCnt = wave_isum(oddCnt);
  if (lane == 0){
    int f = 0;
    if (insane > 0) f = 1;
    else if (evenZero * 4 >= evenCnt * 3 && oddNZ * 4 >= oddCnt * 3) f = 1;
    flags[wid] = f;
  }
}

// ============================================================================
// Kernel 0b: canonicalize params. Weights -> fragment-ordered bf16.
// v8: wg1/wg2/wo (m>=3) get a K-DIMENSION PERMUTATION sigma(p)=(p&3)*16+(p>>2)
// so pt_kernel's A-operands can be written to LDS as single b64 stores in the
// swizzled order 4*(c&15)+(c>>4) (matching q_ws). Dot products are invariant
// under a consistent k-permutation of A and B. wq/wk/wv (m<3) stay natural
// (qkv_kernel's A = feat in natural channel order).
// ============================================================================
__global__ void prep_kernel(PrepPtrs pp, const int* __restrict__ flags,
                            unsigned short* __restrict__ wfrag,
                            unsigned short* __restrict__ wp_bf,
                            float* __restrict__ biases)
{
  const int gid = blockIdx.x * 256 + threadIdx.x;
  const int gstride = gridDim.x * 256;
  const int wflag[6] = {3,5,7,13,17,19};          // wq,wk,wv,wg1,wg2,wo
  for (int idx = gid; idx < 6*4096; idx += gstride){
    int m = idx >> 12;
    int r = idx & 4095;          // ((ks*4+t)*64 + lane)*8 + j
    int j = r & 7;
    int lane = (r >> 3) & 63;
    int kt = r >> 9;
    int ks = kt >> 2, t = kt & 3;
    int o = lane >> 4, rl = lane & 15;
    int pos = ks*32 + o*8 + j;                    // k-slot index in [0,64)
    int kchan = (m >= 3) ? ((pos & 3)*16 + (pos >> 2)) : pos;  // sigma for wg1/wg2/wo
    int src = kchan*64 + t*16 + rl;               // B[k][n] fragment element
    wfrag[idx] = ldbf(pp.w[m], src, flags[wflag[m]]);
  }
  if (blockIdx.x == 0){
    for (int i = threadIdx.x; i < 192; i += 256) wp_bf[i] = ldbf(pp.wp, i, flags[9]);
    const int bflag[11] = {4,6,8,10,11,12,14,15,16,18,20};
    for (int i = threadIdx.x; i < 11*64; i += 256){
      int m = i >> 6;
      biases[i] = ldf(pp.b[m], i & 63, flags[bflag[m]]);
    }
  }
}

// ============================================================================
// Kernel 1: q,k,v = features @ {wq,wk,wv} + bias -> bf16 scratch.
// q_ws: swizzled rows of 64 shorts: (row, c) at row*64 + 4*(c&15) + (c>>4).
// kv_ws: k and v INTERLEAVED per row of 128 shorts: for each rl in [0,16):
//   [rl*8 + 0..3] = k channels {rl, rl+16, rl+32, rl+48}
//   [rl*8 + 4..7] = v channels {rl, rl+16, rl+32, rl+48}
// so pt_kernel's neighbor gather is ONE dwordx4 per lane (k+v fused).
// ============================================================================
__global__ __launch_bounds__(256, 2)
void qkv_kernel(const void* __restrict__ feat,
                const unsigned short* __restrict__ wfrag,
                const float* __restrict__ biases,
                unsigned short* __restrict__ q_ws, unsigned short* __restrict__ kv_ws,
                const int* __restrict__ flags, int N)
{
  const int F_feat = flags[1];
  const int lane = threadIdx.x & 63;
  const int wave = threadIdx.x >> 6;
  const int o = lane >> 4, rl = lane & 15;

  bfrag8 wqf[2][4], wkf[2][4], wvf[2][4];
#pragma unroll
  for (int ks = 0; ks < 2; ks++)
#pragma unroll
    for (int t = 0; t < 4; t++){
      int off = ((ks*4 + t)*64 + lane)*8;
      wqf[ks][t] = gload8(wfrag + off);
      wkf[ks][t] = gload8(wfrag + 4096 + off);
      wvf[ks][t] = gload8(wfrag + 8192 + off);
    }
  float bqC[4], bkC[4], bvC[4];
#pragma unroll
  for (int t = 0; t < 4; t++){
    bqC[t] = biases[0*64 + t*16 + rl];
    bkC[t] = biases[1*64 + t*16 + rl];
    bvC[t] = biases[2*64 + t*16 + rl];
  }

  const int ntiles = (N + 15) >> 4;
  for (int tile = blockIdx.x*4 + wave; tile < ntiles; tile += gridDim.x*4){
    const int n0 = tile * 16;
    int ar = n0 + rl; if (ar >= N) ar = N - 1;
    bfrag8 a[2];
#pragma unroll
    for (int ks = 0; ks < 2; ks++) a[ks] = load8bf(feat, (size_t)ar*64 + ks*32 + o*8, F_feat);

    f32x4 zq[4], zk[4], zv[4];
#pragma unroll
    for (int t = 0; t < 4; t++){
      f32x4 aq = {0.f,0.f,0.f,0.f}, ak = {0.f,0.f,0.f,0.f}, av = {0.f,0.f,0.f,0.f};
#pragma unroll
      for (int ks = 0; ks < 2; ks++){
        aq = mfma16(a[ks], wqf[ks][t], aq);
        ak = mfma16(a[ks], wkf[ks][t], ak);
        av = mfma16(a[ks], wvf[ks][t], av);
      }
      zq[t] = aq; zk[t] = ak; zv[t] = av;
    }
#pragma unroll
    for (int q = 0; q < 4; q++){
      size_t row = n0 + o*4 + q;
      if ((int)row < N){
        uint2 uq;
        uq.x = pk2bf(zq[0][q]+bqC[0], zq[1][q]+bqC[1]);
        uq.y = pk2bf(zq[2][q]+bqC[2], zq[3][q]+bqC[3]);
        *(uint2*)(q_ws + row*64 + 4*rl) = uq;
        uint4 kv;
        kv.x = pk2bf(zk[0][q]+bkC[0], zk[1][q]+bkC[1]);
        kv.y = pk2bf(zk[2][q]+bkC[2], zk[3][q]+bkC[3]);
        kv.z = pk2bf(zv[0][q]+bvC[0], zv[1][q]+bvC[1]);
        kv.w = pk2bf(zv[2][q]+bvC[2], zv[3][q]+bvC[3]);
        *(uint4*)(kv_ws + row*128 + 8*rl) = kv;
      }
    }
  }
}

// ============================================================================
// One point's full compute chain (p-LN -> attn -> GEMM1 -> LN -> GEMM2 ->
// softmax -> GEMM3 -> store). All inputs pre-gathered by the caller.
// v8: C->A bounces are ONE ds_write_b64 per row at [r][4*rl] (sigma-permuted
// wg1/wg2/wo make the swizzled channel order correct for the MFMA k-dim).
// Was 4 strided ds_write_b16 + shifts — the kernel is issue-slot-bound
// (v7: VALU 72% + MFMA 10% + DS), so instruction count is the lever.
// ============================================================================
__device__ __forceinline__ void point_chain(
    int n, int4 kv0, int4 kv1, int4 kv2, int4 kv3,
    uint2 q_c, float res, float rel0, float rel1, float rel2,
    const bfrag8 (&wpf)[4],
    const float (&bpC)[4], const float (&gpC)[4], const float (&bePC)[4],
    const float (&bg1C)[4], const float (&ggC)[4], const float (&beGC)[4],
    const float (&bg2C)[4], const float (&boC)[4],
    unsigned short* xb, unsigned short* yb, const unsigned short* wldsL,
    int o, int rl, int lane, int F_feat, void* __restrict__ out)
{
  // ---- p = relu(LN(rel @ wp + bp)) via MFMA (K padded 3->32) ----
  bfrag8 ap = {0,0,0,0,0,0,0,0};
  if (o == 0){
    ap[0] = (short)f2bf(rel0); ap[1] = (short)f2bf(rel1); ap[2] = (short)f2bf(rel2);
  }
  f32x4 pacc[4];
#pragma unroll
  for (int t = 0; t < 4; t++){
    f32x4 z = {0.f,0.f,0.f,0.f};
    pacc[t] = mfma16(ap, wpf[t], z);
  }
  float p_val[4][4];                        // [t][q], C-layout
#pragma unroll
  for (int q = 0; q < 4; q++){
    float xv[4]; float s = 0.f, s2 = 0.f;
#pragma unroll
    for (int t = 0; t < 4; t++){ xv[t] = pacc[t][q] + bpC[t]; s += xv[t]; s2 += xv[t]*xv[t]; }
    s = row16_sum(s); s2 = row16_sum(s2);
    float mu = s * (1.f/64.f);
    float var = s2 * (1.f/64.f) - mu*mu;
    float rs = rsqrtf(var + 1e-5f);
#pragma unroll
    for (int t = 0; t < 4; t++){
      float a = rs * gpC[t];
      p_val[t][q] = fmaxf(xv[t]*a + (bePC[t] - mu*a), 0.f);
    }
  }

  // ---- attn_in = q - gk + p; single b64 bounce per row (sigma layout) ----
  const float qC0 = bfq(q_c,0), qC1 = bfq(q_c,1), qC2 = bfq(q_c,2), qC3 = bfq(q_c,3);
#pragma unroll
  for (int q = 0; q < 4; q++){
    int4 kvq = (q==0) ? kv0 : (q==1) ? kv1 : (q==2) ? kv2 : kv3;
    float a0 = qC0 - bfk(kvq,0) + p_val[0][q];
    float a1 = qC1 - bfk(kvq,1) + p_val[1][q];
    float a2 = qC2 - bfk(kvq,2) + p_val[2][q];
    float a3 = qC3 - bfk(kvq,3) + p_val[3][q];
    uint2 uu; uu.x = pk2bf(a0, a1); uu.y = pk2bf(a2, a3);
    *(uint2*)(xb + (o*4 + q)*68 + 4*rl) = uu;
  }
  f32x4 hacc[4] = {{0.f,0.f,0.f,0.f},{0.f,0.f,0.f,0.f},{0.f,0.f,0.f,0.f},{0.f,0.f,0.f,0.f}};
#pragma unroll
  for (int ks = 0; ks < 2; ks++){
    bfrag8 af = lds_load8(xb + rl*68 + ks*32 + o*8);
#pragma unroll
    for (int t = 0; t < 4; t++){
      bfrag8 wf = lds_load16B(wldsL + (ks*4 + t)*512);           // wg1 frag (sigma)
      hacc[t] = mfma16(af, wf, hacc[t]);
    }
  }

  // ---- LN + relu -> h; single b64 bounce; GEMM2 ----
#pragma unroll
  for (int q = 0; q < 4; q++){
    float xv[4]; float s = 0.f, s2 = 0.f;
#pragma unroll
    for (int t = 0; t < 4; t++){ xv[t] = hacc[t][q] + bg1C[t]; s += xv[t]; s2 += xv[t]*xv[t]; }
    s = row16_sum(s); s2 = row16_sum(s2);
    float mu = s * (1.f/64.f);
    float var = s2 * (1.f/64.f) - mu*mu;
    float rs = rsqrtf(var + 1e-5f);
    float h0,h1,h2,h3;
    {
      float a = rs * ggC[0]; h0 = fmaxf(xv[0]*a + (beGC[0] - mu*a), 0.f);
      a = rs * ggC[1];       h1 = fmaxf(xv[1]*a + (beGC[1] - mu*a), 0.f);
      a = rs * ggC[2];       h2 = fmaxf(xv[2]*a + (beGC[2] - mu*a), 0.f);
      a = rs * ggC[3];       h3 = fmaxf(xv[3]*a + (beGC[3] - mu*a), 0.f);
    }
    uint2 uu; uu.x = pk2bf(h0, h1); uu.y = pk2bf(h2, h3);
    // note: overwrites xb AFTER attn A-frags were consumed above
    *(uint2*)(xb + (o*4 + q)*68 + 4*rl) = uu;
  }
  f32x4 wacc[4] = {{0.f,0.f,0.f,0.f},{0.f,0.f,0.f,0.f},{0.f,0.f,0.f,0.f},{0.f,0.f,0.f,0.f}};
#pragma unroll
  for (int ks = 0; ks < 2; ks++){
    bfrag8 hf = lds_load8(xb + rl*68 + ks*32 + o*8);
#pragma unroll
    for (int t = 0; t < 4; t++){
      bfrag8 wf = lds_load16B(wldsL + 4096 + (ks*4 + t)*512);    // wg2 frag (sigma)
      wacc[t] = mfma16(hf, wf, wacc[t]);
    }
  }

  // ---- softmax over neighbors (no max-shift: |w| << 88, f32 exp safe) ----
  float y[4];
#pragma unroll
  for (int t = 0; t < 4; t++){
    float se = 0.f, z = 0.f;
#pragma unroll
    for (int q = 0; q < 4; q++){
      int4 kvq = (q==0) ? kv0 : (q==1) ? kv1 : (q==2) ? kv2 : kv3;
      float e = __expf(wacc[t][q] + bg2C[t]);
      se += e;
      z  += e * (bfv(kvq, t) + p_val[t][q]);
    }
    se = xgrp_sum(se); z = xgrp_sum(z);
    y[t] = z * __builtin_amdgcn_rcpf(se);
  }

  // ---- out = y @ wo + bo + residual (y bounce: one b64, sigma layout) ----
  if (o == 0){
    uint2 uu; uu.x = pk2bf(y[0], y[1]); uu.y = pk2bf(y[2], y[3]);
    *(uint2*)(yb + 4*rl) = uu;
  }
  f32x4 oacc[4] = {{0.f,0.f,0.f,0.f},{0.f,0.f,0.f,0.f},{0.f,0.f,0.f,0.f},{0.f,0.f,0.f,0.f}};
#pragma unroll
  for (int ks = 0; ks < 2; ks++){
    bfrag8 yf = lds_load8(yb + ks*32 + o*8);
#pragma unroll
    for (int t = 0; t < 4; t++){
      bfrag8 wf = lds_load16B(wldsL + 2*4096 + (ks*4 + t)*512);  // wo frag (sigma)
      oacc[t] = mfma16(yf, wf, oacc[t]);
    }
  }

  float ov = 0.f;
#pragma unroll
  for (int t = 0; t < 4; t++) if (o == t) ov = oacc[t][0] + boC[t];
  float outv = ov + res;
  if (F_feat) __builtin_nontemporal_store(outv, (float*)out + (size_t)n*64 + lane);
  else        __builtin_nontemporal_store(f2bf(outv), (unsigned short*)out + (size_t)n*64 + lane);
}

// ============================================================================
// Kernel 2: fused point-transformer. 256-thread blocks, one wave per point,
// unrolled x2 with KV-ONLY cross-chain prefetch (v7 structure, measured
// 98µs steady / FETCH 94MB / WRITE 14.5MB — keep intact). v8 only trims
// issue slots inside point_chain (b64 bounces + sigma weights).
// ============================================================================
__global__ __launch_bounds__(256, 3)
void pt_kernel(const void* __restrict__ points,
               const void* __restrict__ feat,
               const int* __restrict__ nidx,
               const unsigned short* __restrict__ q_ws,
               const unsigned short* __restrict__ kv_ws,
               const unsigned short* __restrict__ wfrag,
               const unsigned short* __restrict__ wp_bf,
               const float* __restrict__ biases,
               const int* __restrict__ flags, void* __restrict__ out, int N)
{
  __shared__ unsigned short xbuf[4][16][68];   // per-wave C<->A bounce (stride 68)
  __shared__ unsigned short ybuf[4][64];
  __shared__ __align__(16) unsigned short wlds[3*4096]; // wg1 | wg2 | wo fragments

  const int F_pts = flags[0], F_feat = flags[1];
  const int lane = threadIdx.x & 63;
  const int wave = threadIdx.x >> 6;
  const int o = lane >> 4, rl = lane & 15;

  // ---- stage wg1/wg2/wo fragments into LDS (once per block) ----
  {
    const unsigned short* wsrc = wfrag + 3*4096;
    for (int i = threadIdx.x*8; i < 3*4096; i += 256*8)
      *(int4*)(wlds + i) = *(const int4*)(wsrc + i);
  }
  __syncthreads();

  // ---- per-wave constants ----
  bfrag8 wpf[4];
#pragma unroll
  for (int t = 0; t < 4; t++){
    bfrag8 a = {0,0,0,0,0,0,0,0};
    if (o == 0){
#pragma unroll
      for (int j = 0; j < 3; j++) a[j] = (short)wp_bf[j*64 + t*16 + rl];
    }
    wpf[t] = a;
  }
  float bpC[4], gpC[4], bePC[4], bg1C[4], ggC[4], beGC[4], bg2C[4], boC[4];
#pragma unroll
  for (int t = 0; t < 4; t++){
    int c = t*16 + rl;
    bpC[t]  = biases[3*64 + c];  gpC[t]  = biases[4*64 + c];  bePC[t] = biases[5*64 + c];
    bg1C[t] = biases[6*64 + c];  ggC[t]  = biases[7*64 + c];  beGC[t] = biases[8*64 + c];
    bg2C[t] = biases[9*64 + c];  boC[t]  = biases[10*64 + c];
  }

  unsigned short* xb = &xbuf[wave][0][0];
  unsigned short* yb = &ybuf[wave][0];
  const unsigned short* wldsL = wlds + lane*8;   // per-lane base; rest is imm offsets

  const int ws = gridDim.x * 4;
  const int n_first = blockIdx.x*4 + wave;

  // ---- pipeline state: indices for A-role and B-role points; A's kv live ----
  int jrA=0, jqA0=0, jqA1=0, jqA2=0, jqA3=0;
  int jrB=0, jqB0=0, jqB1=0, jqB2=0, jqB3=0;
  int4 kvA0={0,0,0,0}, kvA1={0,0,0,0}, kvA2={0,0,0,0}, kvA3={0,0,0,0};
  if (n_first < N){
    jrA  = nidx[n_first*16 + rl];
    jqA0 = nidx[n_first*16 + o*4 + 0];
    jqA1 = nidx[n_first*16 + o*4 + 1];
    jqA2 = nidx[n_first*16 + o*4 + 2];
    jqA3 = nidx[n_first*16 + o*4 + 3];
    kvA0 = *(const int4*)(kv_ws + (size_t)jqA0*128 + 8*rl);
    kvA1 = *(const int4*)(kv_ws + (size_t)jqA1*128 + 8*rl);
    kvA2 = *(const int4*)(kv_ws + (size_t)jqA2*128 + 8*rl);
    kvA3 = *(const int4*)(kv_ws + (size_t)jqA3*128 + 8*rl);
    if (n_first + ws < N){
      jrB  = nidx[(n_first+ws)*16 + rl];
      jqB0 = nidx[(n_first+ws)*16 + o*4 + 0];
      jqB1 = nidx[(n_first+ws)*16 + o*4 + 1];
      jqB2 = nidx[(n_first+ws)*16 + o*4 + 2];
      jqB3 = nidx[(n_first+ws)*16 + o*4 + 3];
    }
  }

  for (int n = n_first; n < N; n += 2*ws){
    const int nA = n, nB = n + ws, nC = n + 2*ws, nD = n + 3*ws;
    const bool hasB = (nB < N), hasC = (nC < N), hasD = (nD < N);

    // ---- A's own gathers (covered by A's p-LN, v4-proven placement) ----
    uint2 qA = *(const uint2*)(q_ws + (size_t)nA*64 + 4*rl);
    const float resA = ldf(feat, (size_t)nA*64 + lane, F_feat);
    float relA0 = ldf(points, (size_t)jrA*3 + 0, F_pts) - ldf(points, (size_t)nA*3 + 0, F_pts);
    float relA1 = ldf(points, (size_t)jrA*3 + 1, F_pts) - ldf(points, (size_t)nA*3 + 1, F_pts);
    float relA2 = ldf(points, (size_t)jrA*3 + 2, F_pts) - ldf(points, (size_t)nA*3 + 2, F_pts);

    // ---- issue B's kv NOW (16 VGPR live across chain A; first use ~1500cy) ----
    int4 kvB0={0,0,0,0}, kvB1={0,0,0,0}, kvB2={0,0,0,0}, kvB3={0,0,0,0};
    if (hasB){
      kvB0 = *(const int4*)(kv_ws + (size_t)jqB0*128 + 8*rl);
      kvB1 = *(const int4*)(kv_ws + (size_t)jqB1*128 + 8*rl);
      kvB2 = *(const int4*)(kv_ws + (size_t)jqB2*128 + 8*rl);
      kvB3 = *(const int4*)(kv_ws + (size_t)jqB3*128 + 8*rl);
    }
    __builtin_amdgcn_sched_barrier(0);     // pin: loads above must ISSUE here

    // ---- refill A-role indices for nC (latency hidden under chain A) ----
    int jrA2=0, jqA2_0=0, jqA2_1=0, jqA2_2=0, jqA2_3=0;
    if (hasC){
      jrA2   = nidx[nC*16 + rl];
      jqA2_0 = nidx[nC*16 + o*4 + 0];
      jqA2_1 = nidx[nC*16 + o*4 + 1];
      jqA2_2 = nidx[nC*16 + o*4 + 2];
      jqA2_3 = nidx[nC*16 + o*4 + 3];
    }

    // ---- chain A ----
    point_chain(nA, kvA0, kvA1, kvA2, kvA3, qA, resA, relA0, relA1, relA2,
                wpf, bpC, gpC, bePC, bg1C, ggC, beGC, bg2C, boC,
                xb, yb, wldsL, o, rl, lane, F_feat, out);

    if (hasB){
      // ---- B's own gathers ----
      uint2 qB = *(const uint2*)(q_ws + (size_t)nB*64 + 4*rl);
      const float resB = ldf(feat, (size_t)nB*64 + lane, F_feat);
      float relB0 = ldf(points, (size_t)jrB*3 + 0, F_pts) - ldf(points, (size_t)nB*3 + 0, F_pts);
      float relB1 = ldf(points, (size_t)jrB*3 + 1, F_pts) - ldf(points, (size_t)nB*3 + 1, F_pts);
      float relB2 = ldf(points, (size_t)jrB*3 + 2, F_pts) - ldf(points, (size_t)nB*3 + 2, F_pts);

      // ---- issue next-A kv (for nC), hidden under chain B ----
      int4 kvN0={0,0,0,0}, kvN1={0,0,0,0}, kvN2={0,0,0,0}, kvN3={0,0,0,0};
      if (hasC){
        kvN0 = *(const int4*)(kv_ws + (size_t)jqA2_0*128 + 8*rl);
        kvN1 = *(const int4*)(kv_ws + (size_t)jqA2_1*128 + 8*rl);
        kvN2 = *(const int4*)(kv_ws + (size_t)jqA2_2*128 + 8*rl);
        kvN3 = *(const int4*)(kv_ws + (size_t)jqA2_3*128 + 8*rl);
      }
      __builtin_amdgcn_sched_barrier(0);

      // ---- refill B-role indices for nD ----
      if (hasD){
        jrB  = nidx[nD*16 + rl];
        jqB0 = nidx[nD*16 + o*4 + 0];
        jqB1 = nidx[nD*16 + o*4 + 1];
        jqB2 = nidx[nD*16 + o*4 + 2];
        jqB3 = nidx[nD*16 + o*4 + 3];
      }

      // ---- chain B ----
      point_chain(nB, kvB0, kvB1, kvB2, kvB3, qB, resB, relB0, relB1, relB2,
                  wpf, bpC, gpC, bePC, bg1C, ggC, beGC, bg2C, boC,
                  xb, yb, wldsL, o, rl, lane, F_feat, out);

      // ---- rotate A-role state ----
      kvA0 = kvN0; kvA1 = kvN1; kvA2 = kvN2; kvA3 = kvN3;
      jrA = jrA2; jqA0 = jqA2_0; jqA1 = jqA2_1; jqA2 = jqA2_2; jqA3 = jqA2_3;
    }
  }
}

// ============================================================================
extern "C" void kernel_launch(void* const* d_in, const int* in_sizes, int n_in,
                              void* d_out, int out_size, void* d_ws, size_t ws_size,
                              hipStream_t stream)
{
  const int N = in_sizes[1] / 64;

  unsigned short* q_ws  = (unsigned short*)d_ws;           // N*64 shorts
  unsigned short* kv_ws = q_ws + (size_t)N * 64;           // N*128 shorts (k|v interleaved)
  char* base = (char*)d_ws + (size_t)3 * N * 64 * sizeof(unsigned short);
  int*            flags  = (int*)base;                            // 128 B
  unsigned short* wfrag  = (unsigned short*)(base + 256);         // 49152 B
  unsigned short* wp_bf  = (unsigned short*)(base + 256 + 49152); // 384 B (pad 512)
  float*          biases = (float*)(base + 256 + 49152 + 512);    // 2816 B

  Ptrs ptrs;
  for (int i = 0; i < 21; i++){ ptrs.p[i] = d_in[i]; ptrs.n[i] = in_sizes[i]; }
  PrepPtrs pp;
  pp.w[0] = d_in[3];  pp.w[1] = d_in[5];  pp.w[2] = d_in[7];
  pp.w[3] = d_in[13]; pp.w[4] = d_in[17]; pp.w[5] = d_in[19];
  pp.wp = d_in[9];
  pp.b[0] = d_in[4];  pp.b[1] = d_in[6];  pp.b[2] = d_in[8];  pp.b[3] = d_in[10];
  pp.b[4] = d_in[11]; pp.b[5] = d_in[12]; pp.b[6] = d_in[14]; pp.b[7] = d_in[15];
  pp.b[8] = d_in[16]; pp.b[9] = d_in[18]; pp.b[10] = d_in[20];

  detect_kernel<<<6, 256, 0, stream>>>(ptrs, flags);
  prep_kernel<<<32, 256, 0, stream>>>(pp, flags, wfrag, wp_bf, biases);
  qkv_kernel<<<512, 256, 0, stream>>>(d_in[1], wfrag, biases, q_ws, kv_ws, flags, N);
  pt_kernel<<<2048, 256, 0, stream>>>(d_in[0], d_in[1], (const int*)d_in[2], q_ws, kv_ws,
                                      wfrag, wp_bf, biases, flags, d_out, N);
}

// Round 14
// 202.720 us; speedup vs baseline: 1.1371x; 1.1371x over previous
//
#include <hip/hip_runtime.h>

// ---------- types ----------
typedef __attribute__((ext_vector_type(8))) short bfrag8;   // 8 bf16 bit patterns (4 VGPRs)
typedef __attribute__((ext_vector_type(4))) short bfrag4;
typedef __attribute__((ext_vector_type(4))) float f32x4;

#if defined(__has_builtin)
#if __has_builtin(__builtin_amdgcn_cvt_pk_bf16_f32)
#define HAVE_PK_BF16 1
#endif
#endif

// ---------- bf16 helpers ----------
__device__ __forceinline__ float bf2f(unsigned short h){
  unsigned u = ((unsigned)h) << 16;
  return __builtin_bit_cast(float, u);
}
__device__ __forceinline__ unsigned short f2bf(float f){
  unsigned u = __builtin_bit_cast(unsigned, f);
  u = u + 0x7FFFu + ((u >> 16) & 1u);        // round-to-nearest-even
  return (unsigned short)(u >> 16);
}
// pack two f32 -> two bf16 in one dword (lo=a, hi=b); single instr on gfx950
__device__ __forceinline__ unsigned pk2bf(float a, float b){
#ifdef HAVE_PK_BF16
  typedef __attribute__((ext_vector_type(2))) __bf16 bf16x2_t;
  bf16x2_t r = __builtin_amdgcn_cvt_pk_bf16_f32(a, b);
  return __builtin_bit_cast(unsigned, r);
#else
  return (unsigned)f2bf(a) | ((unsigned)f2bf(b) << 16);
#endif
}
__device__ __forceinline__ bfrag8 gload8(const unsigned short* p){ // 16B-aligned global, bf16
  int4 v = *(const int4*)p;
  return __builtin_bit_cast(bfrag8, v);
}
__device__ __forceinline__ bfrag8 lds_load8(const unsigned short* p){ // 8B-aligned LDS
  bfrag4 lo = *(const bfrag4*)p;
  bfrag4 hi = *(const bfrag4*)(p + 4);
  bfrag8 r;
#pragma unroll
  for (int j = 0; j < 4; j++){ r[j] = lo[j]; r[4+j] = hi[j]; }
  return r;
}
__device__ __forceinline__ bfrag8 lds_load16B(const unsigned short* p){ // 16B-aligned LDS -> ds_read_b128
  int4 v = *(const int4*)p;
  return __builtin_bit_cast(bfrag8, v);
}
__device__ __forceinline__ f32x4 mfma16(bfrag8 a, bfrag8 b, f32x4 c){
  return __builtin_amdgcn_mfma_f32_16x16x32_bf16(a, b, c, 0, 0, 0);
}

// bf16 select from packed kv word (compile-time t after unroll).
// k lives in .x/.y, v lives in .z/.w of the int4.
__device__ __forceinline__ float bfk(int4 v, int t){
  unsigned w = (t < 2) ? (unsigned)v.x : (unsigned)v.y;
  unsigned h = (t & 1) ? (w >> 16) : (w & 0xFFFFu);
  return bf2f((unsigned short)h);
}
__device__ __forceinline__ float bfv(int4 v, int t){
  unsigned w = (t < 2) ? (unsigned)v.z : (unsigned)v.w;
  unsigned h = (t & 1) ? (w >> 16) : (w & 0xFFFFu);
  return bf2f((unsigned short)h);
}
__device__ __forceinline__ float bfq(uint2 v, int t){
  unsigned w = (t < 2) ? v.x : v.y;
  unsigned h = (t & 1) ? (w >> 16) : (w & 0xFFFFu);
  return bf2f((unsigned short)h);
}

// ---------- dtype-dispatched accessors (flag: 1 = tensor is f32) ----------
__device__ __forceinline__ float ldf(const void* p, size_t i, int f32){
  return f32 ? ((const float*)p)[i] : bf2f(((const unsigned short*)p)[i]);
}
__device__ __forceinline__ unsigned short ldbf(const void* p, size_t i, int f32){
  return f32 ? f2bf(((const float*)p)[i]) : ((const unsigned short*)p)[i];
}
__device__ __forceinline__ bfrag8 load8bf(const void* p, size_t base, int f32){
  if (f32){
    const float* f = (const float*)p + base;
    float4 x = *(const float4*)f;
    float4 y = *(const float4*)(f + 4);
    bfrag8 r;
    r[0]=(short)f2bf(x.x); r[1]=(short)f2bf(x.y); r[2]=(short)f2bf(x.z); r[3]=(short)f2bf(x.w);
    r[4]=(short)f2bf(y.x); r[5]=(short)f2bf(y.y); r[6]=(short)f2bf(y.z); r[7]=(short)f2bf(y.w);
    return r;
  }
  return gload8((const unsigned short*)p + base);
}

// ---------- reductions ----------
template<int CTRL>
__device__ __forceinline__ float dpp_add(float x){
  int xi = __builtin_bit_cast(int, x);
  int yi = __builtin_amdgcn_update_dpp(0, xi, CTRL, 0xF, 0xF, true);
  return x + __builtin_bit_cast(float, yi);
}
__device__ __forceinline__ float row16_sum(float x){
  x = dpp_add<0xB1>(x);    // quad_perm [1,0,3,2]  : + lane^1
  x = dpp_add<0x4E>(x);    // quad_perm [2,3,0,1]  : + lane^2
  x = dpp_add<0x141>(x);   // row_half_mirror      : + other quad
  x = dpp_add<0x140>(x);   // row_mirror           : + other 8-group
  return x;
}
__device__ __forceinline__ float xgrp_sum(float x){
  x += __shfl_xor(x, 16, 64);
  x += __shfl_xor(x, 32, 64);
  return x;
}
__device__ __forceinline__ int wave_isum(int x){
#pragma unroll
  for (int s = 1; s < 64; s <<= 1) x += __shfl_xor(x, s, 64);
  return x;
}

// ============================================================================
// Kernel 0a: dtype sniffing — parallel, one wave per tensor.
// ============================================================================
struct Ptrs { const void* p[21]; int n[21]; };
struct PrepPtrs { const void* w[6]; const void* wp; const void* b[11]; };

__global__ void detect_kernel(Ptrs ptrs, int* flags){
  const int lane = threadIdx.x & 63;
  const int wid = blockIdx.x * 4 + (threadIdx.x >> 6);
  if (wid >= 21) return;
  if (wid == 2){ if (lane == 0) flags[2] = 0; return; }   // neighbor_idx is int32

  const unsigned short* p = (const unsigned short*)ptrs.p[wid];
  int m = ptrs.n[wid]; if (m > 128) m = 128;
  int insane = 0, evenZero = 0, evenCnt = 0, oddNZ = 0, oddCnt = 0;
#pragma unroll
  for (int s = 0; s < 2; s++){
    int i = lane + s*64;
    if (i < m){
      unsigned short h = p[i];
      int e = (h >> 7) & 0xFF;
      bool z = (h & 0x7FFF) == 0;
      if (!z && (e == 0xFF || e < 90 || e > 140)) insane++;
      if (i & 1){ oddCnt++;  if (!z) oddNZ++; }
      else      { evenCnt++; if (z)  evenZero++; }
    }
  }
  insane = wave_isum(insane);
  evenZero = wave_isum(evenZero); evenCnt = wave_isum(evenCnt);
  oddNZ = wave_isum(oddNZ);       oddCnt = wave_isum(oddCnt);
  if (lane == 0){
    int f = 0;
    if (insane > 0) f = 1;
    else if (evenZero * 4 >= evenCnt * 3 && oddNZ * 4 >= oddCnt * 3) f = 1;
    flags[wid] = f;
  }
}

// ============================================================================
// Kernel 0b: canonicalize params. Weights -> fragment-ordered bf16.
// ============================================================================
__global__ void prep_kernel(PrepPtrs pp, const int* __restrict__ flags,
                            unsigned short* __restrict__ wfrag,
                            unsigned short* __restrict__ wp_bf,
                            float* __restrict__ biases)
{
  const int gid = blockIdx.x * 256 + threadIdx.x;
  const int gstride = gridDim.x * 256;
  const int wflag[6] = {3,5,7,13,17,19};          // wq,wk,wv,wg1,wg2,wo
  for (int idx = gid; idx < 6*4096; idx += gstride){
    int m = idx >> 12;
    int r = idx & 4095;          // ((ks*4+t)*64 + lane)*8 + j
    int j = r & 7;
    int lane = (r >> 3) & 63;
    int kt = r >> 9;
    int ks = kt >> 2, t = kt & 3;
    int o = lane >> 4, rl = lane & 15;
    int src = (ks*32 + o*8 + j)*64 + t*16 + rl;   // B[k][n] fragment element
    wfrag[idx] = ldbf(pp.w[m], src, flags[wflag[m]]);
  }
  if (blockIdx.x == 0){
    for (int i = threadIdx.x; i < 192; i += 256) wp_bf[i] = ldbf(pp.wp, i, flags[9]);
    const int bflag[11] = {4,6,8,10,11,12,14,15,16,18,20};
    for (int i = threadIdx.x; i < 11*64; i += 256){
      int m = i >> 6;
      biases[i] = ldf(pp.b[m], i & 63, flags[bflag[m]]);
    }
  }
}

// ============================================================================
// Kernel 1: q,k,v = features @ {wq,wk,wv} + bias -> bf16 scratch.
// q_ws: swizzled rows of 64 shorts: (row, c) at row*64 + 4*(c&15) + (c>>4).
// kv_ws: k and v INTERLEAVED per row of 128 shorts: for each rl in [0,16):
//   [rl*8 + 0..3] = k channels {rl, rl+16, rl+32, rl+48}
//   [rl*8 + 4..7] = v channels {rl, rl+16, rl+32, rl+48}
// so pt_kernel's neighbor gather is ONE dwordx4 per lane (k+v fused).
// ============================================================================
__global__ __launch_bounds__(256, 2)
void qkv_kernel(const void* __restrict__ feat,
                const unsigned short* __restrict__ wfrag,
                const float* __restrict__ biases,
                unsigned short* __restrict__ q_ws, unsigned short* __restrict__ kv_ws,
                const int* __restrict__ flags, int N)
{
  const int F_feat = flags[1];
  const int lane = threadIdx.x & 63;
  const int wave = threadIdx.x >> 6;
  const int o = lane >> 4, rl = lane & 15;

  bfrag8 wqf[2][4], wkf[2][4], wvf[2][4];
#pragma unroll
  for (int ks = 0; ks < 2; ks++)
#pragma unroll
    for (int t = 0; t < 4; t++){
      int off = ((ks*4 + t)*64 + lane)*8;
      wqf[ks][t] = gload8(wfrag + off);
      wkf[ks][t] = gload8(wfrag + 4096 + off);
      wvf[ks][t] = gload8(wfrag + 8192 + off);
    }
  float bqC[4], bkC[4], bvC[4];
#pragma unroll
  for (int t = 0; t < 4; t++){
    bqC[t] = biases[0*64 + t*16 + rl];
    bkC[t] = biases[1*64 + t*16 + rl];
    bvC[t] = biases[2*64 + t*16 + rl];
  }

  const int ntiles = (N + 15) >> 4;
  for (int tile = blockIdx.x*4 + wave; tile < ntiles; tile += gridDim.x*4){
    const int n0 = tile * 16;
    int ar = n0 + rl; if (ar >= N) ar = N - 1;
    bfrag8 a[2];
#pragma unroll
    for (int ks = 0; ks < 2; ks++) a[ks] = load8bf(feat, (size_t)ar*64 + ks*32 + o*8, F_feat);

    f32x4 zq[4], zk[4], zv[4];
#pragma unroll
    for (int t = 0; t < 4; t++){
      f32x4 aq = {0.f,0.f,0.f,0.f}, ak = {0.f,0.f,0.f,0.f}, av = {0.f,0.f,0.f,0.f};
#pragma unroll
      for (int ks = 0; ks < 2; ks++){
        aq = mfma16(a[ks], wqf[ks][t], aq);
        ak = mfma16(a[ks], wkf[ks][t], ak);
        av = mfma16(a[ks], wvf[ks][t], av);
      }
      zq[t] = aq; zk[t] = ak; zv[t] = av;
    }
#pragma unroll
    for (int q = 0; q < 4; q++){
      size_t row = n0 + o*4 + q;
      if ((int)row < N){
        uint2 uq;
        uq.x = pk2bf(zq[0][q]+bqC[0], zq[1][q]+bqC[1]);
        uq.y = pk2bf(zq[2][q]+bqC[2], zq[3][q]+bqC[3]);
        *(uint2*)(q_ws + row*64 + 4*rl) = uq;
        uint4 kv;
        kv.x = pk2bf(zk[0][q]+bkC[0], zk[1][q]+bkC[1]);
        kv.y = pk2bf(zk[2][q]+bkC[2], zk[3][q]+bkC[3]);
        kv.z = pk2bf(zv[0][q]+bvC[0], zv[1][q]+bvC[1]);
        kv.w = pk2bf(zv[2][q]+bvC[2], zv[3][q]+bvC[3]);
        *(uint4*)(kv_ws + row*128 + 8*rl) = kv;
      }
    }
  }
}

// ============================================================================
// One point's full compute chain (p-LN -> attn -> GEMM1 -> LN -> GEMM2 ->
// softmax -> GEMM3 -> store). All inputs pre-gathered by the caller.
// ============================================================================
__device__ __forceinline__ void point_chain(
    int n, int4 kv0, int4 kv1, int4 kv2, int4 kv3,
    uint2 q_c, float res, float rel0, float rel1, float rel2,
    const bfrag8 (&wpf)[4],
    const float (&bpC)[4], const float (&gpC)[4], const float (&bePC)[4],
    const float (&bg1C)[4], const float (&ggC)[4], const float (&beGC)[4],
    const float (&bg2C)[4], const float (&boC)[4],
    unsigned short* xb, unsigned short* yb, const unsigned short* wldsL,
    int o, int rl, int lane, int F_feat, void* __restrict__ out)
{
  // ---- p = relu(LN(rel @ wp + bp)) via MFMA (K padded 3->32) ----
  bfrag8 ap = {0,0,0,0,0,0,0,0};
  if (o == 0){
    ap[0] = (short)f2bf(rel0); ap[1] = (short)f2bf(rel1); ap[2] = (short)f2bf(rel2);
  }
  f32x4 pacc[4];
#pragma unroll
  for (int t = 0; t < 4; t++){
    f32x4 z = {0.f,0.f,0.f,0.f};
    pacc[t] = mfma16(ap, wpf[t], z);
  }
  float p_val[4][4];                        // [t][q], C-layout
#pragma unroll
  for (int q = 0; q < 4; q++){
    float xv[4]; float s = 0.f, s2 = 0.f;
#pragma unroll
    for (int t = 0; t < 4; t++){ xv[t] = pacc[t][q] + bpC[t]; s += xv[t]; s2 += xv[t]*xv[t]; }
    s = row16_sum(s); s2 = row16_sum(s2);
    float mu = s * (1.f/64.f);
    float var = s2 * (1.f/64.f) - mu*mu;
    float rs = rsqrtf(var + 1e-5f);
#pragma unroll
    for (int t = 0; t < 4; t++){
      float a = rs * gpC[t];
      p_val[t][q] = fmaxf(xv[t]*a + (bePC[t] - mu*a), 0.f);
    }
  }

  // ---- attn_in = q - gk + p in C-layout; bounce C->A (paired bf16 pack) ----
#pragma unroll
  for (int q = 0; q < 4; q++){
    int4 kvq = (q==0) ? kv0 : (q==1) ? kv1 : (q==2) ? kv2 : kv3;
    float a0 = bfq(q_c,0) - bfk(kvq,0) + p_val[0][q];
    float a1 = bfq(q_c,1) - bfk(kvq,1) + p_val[1][q];
    float a2 = bfq(q_c,2) - bfk(kvq,2) + p_val[2][q];
    float a3 = bfq(q_c,3) - bfk(kvq,3) + p_val[3][q];
    unsigned u01 = pk2bf(a0, a1), u23 = pk2bf(a2, a3);
    int r = o*4 + q;
    xb[r*68 + 0*16 + rl] = (unsigned short)u01;
    xb[r*68 + 1*16 + rl] = (unsigned short)(u01 >> 16);
    xb[r*68 + 2*16 + rl] = (unsigned short)u23;
    xb[r*68 + 3*16 + rl] = (unsigned short)(u23 >> 16);
  }
  f32x4 hacc[4] = {{0.f,0.f,0.f,0.f},{0.f,0.f,0.f,0.f},{0.f,0.f,0.f,0.f},{0.f,0.f,0.f,0.f}};
#pragma unroll
  for (int ks = 0; ks < 2; ks++){
    bfrag8 af = lds_load8(xb + rl*68 + ks*32 + o*8);
#pragma unroll
    for (int t = 0; t < 4; t++){
      bfrag8 wf = lds_load16B(wldsL + (ks*4 + t)*512);           // wg1 frag
      hacc[t] = mfma16(af, wf, hacc[t]);
    }
  }

  // ---- LN + relu -> h; bounce C->A; GEMM2 ----
#pragma unroll
  for (int q = 0; q < 4; q++){
    float xv[4]; float s = 0.f, s2 = 0.f;
#pragma unroll
    for (int t = 0; t < 4; t++){ xv[t] = hacc[t][q] + bg1C[t]; s += xv[t]; s2 += xv[t]*xv[t]; }
    s = row16_sum(s); s2 = row16_sum(s2);
    float mu = s * (1.f/64.f);
    float var = s2 * (1.f/64.f) - mu*mu;
    float rs = rsqrtf(var + 1e-5f);
    float h0,h1,h2,h3;
    {
      float a = rs * ggC[0]; h0 = fmaxf(xv[0]*a + (beGC[0] - mu*a), 0.f);
      a = rs * ggC[1];       h1 = fmaxf(xv[1]*a + (beGC[1] - mu*a), 0.f);
      a = rs * ggC[2];       h2 = fmaxf(xv[2]*a + (beGC[2] - mu*a), 0.f);
      a = rs * ggC[3];       h3 = fmaxf(xv[3]*a + (beGC[3] - mu*a), 0.f);
    }
    unsigned u01 = pk2bf(h0, h1);
    unsigned u23 = pk2bf(h2, h3);
    int r = o*4 + q;
    // note: overwrites xb AFTER attn A-frags were consumed above
    xb[r*68 + 0*16 + rl] = (unsigned short)u01;
    xb[r*68 + 1*16 + rl] = (unsigned short)(u01 >> 16);
    xb[r*68 + 2*16 + rl] = (unsigned short)u23;
    xb[r*68 + 3*16 + rl] = (unsigned short)(u23 >> 16);
  }
  f32x4 wacc[4] = {{0.f,0.f,0.f,0.f},{0.f,0.f,0.f,0.f},{0.f,0.f,0.f,0.f},{0.f,0.f,0.f,0.f}};
#pragma unroll
  for (int ks = 0; ks < 2; ks++){
    bfrag8 hf = lds_load8(xb + rl*68 + ks*32 + o*8);
#pragma unroll
    for (int t = 0; t < 4; t++){
      bfrag8 wf = lds_load16B(wldsL + 4096 + (ks*4 + t)*512);    // wg2 frag
      wacc[t] = mfma16(hf, wf, wacc[t]);
    }
  }

  // ---- softmax over neighbors (no max-shift: |w| << 88, f32 exp safe) ----
  float y[4];
#pragma unroll
  for (int t = 0; t < 4; t++){
    float se = 0.f, z = 0.f;
#pragma unroll
    for (int q = 0; q < 4; q++){
      int4 kvq = (q==0) ? kv0 : (q==1) ? kv1 : (q==2) ? kv2 : kv3;
      float e = __expf(wacc[t][q] + bg2C[t]);
      se += e;
      z  += e * (bfv(kvq, t) + p_val[t][q]);
    }
    se = xgrp_sum(se); z = xgrp_sum(z);
    y[t] = z * __builtin_amdgcn_rcpf(se);
  }

  // ---- out = y @ wo + bo + residual ----
  if (o == 0){
    unsigned u01 = pk2bf(y[0], y[1]), u23 = pk2bf(y[2], y[3]);
    yb[0*16 + rl] = (unsigned short)u01;
    yb[1*16 + rl] = (unsigned short)(u01 >> 16);
    yb[2*16 + rl] = (unsigned short)u23;
    yb[3*16 + rl] = (unsigned short)(u23 >> 16);
  }
  f32x4 oacc[4] = {{0.f,0.f,0.f,0.f},{0.f,0.f,0.f,0.f},{0.f,0.f,0.f,0.f},{0.f,0.f,0.f,0.f}};
#pragma unroll
  for (int ks = 0; ks < 2; ks++){
    bfrag8 yf = lds_load8(yb + ks*32 + o*8);
#pragma unroll
    for (int t = 0; t < 4; t++){
      bfrag8 wf = lds_load16B(wldsL + 2*4096 + (ks*4 + t)*512);  // wo frag
      oacc[t] = mfma16(yf, wf, oacc[t]);
    }
  }

  float ov = 0.f;
#pragma unroll
  for (int t = 0; t < 4; t++) if (o == t) ov = oacc[t][0] + boC[t];
  float outv = ov + res;
  if (F_feat) __builtin_nontemporal_store(outv, (float*)out + (size_t)n*64 + lane);
  else        __builtin_nontemporal_store(f2bf(outv), (unsigned short*)out + (size_t)n*64 + lane);
}

// ============================================================================
// Kernel 2: fused point-transformer. 256-thread blocks, one wave per point,
// unrolled x2 with KV-ONLY cross-chain prefetch.
//
// == v7 verbatim (best measured: 98µs steady, FETCH 94MB, WRITE 14.5MB,
// VALU 72%). v8's sigma-weights + b64-bounce regressed to 122µs with a
// +46MB WRITE / +33MB FETCH scratch-like signature — reverted per the
// pre-committed decision rule.
//
// Post-mortems baked in:
//  * v3: full-state rotate pipeline -> compiler SANK loads (no overlap).
//  * v6: full-state prefetch (~50 VGPR) -> regalloc SPILLED (WRITE 415MB).
//  * v7 fix: cross-chain state = ONLY 4 kv int4s (16 VGPR); q/res/rel at
//    each chain's own top (p-LN covers); sched_barrier pins issue; x2
//    unroll gives B's kv the whole chain-A window (~1500cy).
//  * v5: +waves thrashed L2; v8: bounce/sigma rewrite induced spills.
// ============================================================================
__global__ __launch_bounds__(256, 3)
void pt_kernel(const void* __restrict__ points,
               const void* __restrict__ feat,
               const int* __restrict__ nidx,
               const unsigned short* __restrict__ q_ws,
               const unsigned short* __restrict__ kv_ws,
               const unsigned short* __restrict__ wfrag,
               const unsigned short* __restrict__ wp_bf,
               const float* __restrict__ biases,
               const int* __restrict__ flags, void* __restrict__ out, int N)
{
  __shared__ unsigned short xbuf[4][16][68];   // per-wave C<->A bounce (stride 68)
  __shared__ unsigned short ybuf[4][64];
  __shared__ __align__(16) unsigned short wlds[3*4096]; // wg1 | wg2 | wo fragments

  const int F_pts = flags[0], F_feat = flags[1];
  const int lane = threadIdx.x & 63;
  const int wave = threadIdx.x >> 6;
  const int o = lane >> 4, rl = lane & 15;

  // ---- stage wg1/wg2/wo fragments into LDS (once per block) ----
  {
    const unsigned short* wsrc = wfrag + 3*4096;
    for (int i = threadIdx.x*8; i < 3*4096; i += 256*8)
      *(int4*)(wlds + i) = *(const int4*)(wsrc + i);
  }
  __syncthreads();

  // ---- per-wave constants ----
  bfrag8 wpf[4];
#pragma unroll
  for (int t = 0; t < 4; t++){
    bfrag8 a = {0,0,0,0,0,0,0,0};
    if (o == 0){
#pragma unroll
      for (int j = 0; j < 3; j++) a[j] = (short)wp_bf[j*64 + t*16 + rl];
    }
    wpf[t] = a;
  }
  float bpC[4], gpC[4], bePC[4], bg1C[4], ggC[4], beGC[4], bg2C[4], boC[4];
#pragma unroll
  for (int t = 0; t < 4; t++){
    int c = t*16 + rl;
    bpC[t]  = biases[3*64 + c];  gpC[t]  = biases[4*64 + c];  bePC[t] = biases[5*64 + c];
    bg1C[t] = biases[6*64 + c];  ggC[t]  = biases[7*64 + c];  beGC[t] = biases[8*64 + c];
    bg2C[t] = biases[9*64 + c];  boC[t]  = biases[10*64 + c];
  }

  unsigned short* xb = &xbuf[wave][0][0];
  unsigned short* yb = &ybuf[wave][0];
  const unsigned short* wldsL = wlds + lane*8;   // per-lane base; rest is imm offsets

  const int ws = gridDim.x * 4;
  const int n_first = blockIdx.x*4 + wave;

  // ---- pipeline state: indices for A-role and B-role points; A's kv live ----
  int jrA=0, jqA0=0, jqA1=0, jqA2=0, jqA3=0;
  int jrB=0, jqB0=0, jqB1=0, jqB2=0, jqB3=0;
  int4 kvA0={0,0,0,0}, kvA1={0,0,0,0}, kvA2={0,0,0,0}, kvA3={0,0,0,0};
  if (n_first < N){
    jrA  = nidx[n_first*16 + rl];
    jqA0 = nidx[n_first*16 + o*4 + 0];
    jqA1 = nidx[n_first*16 + o*4 + 1];
    jqA2 = nidx[n_first*16 + o*4 + 2];
    jqA3 = nidx[n_first*16 + o*4 + 3];
    kvA0 = *(const int4*)(kv_ws + (size_t)jqA0*128 + 8*rl);
    kvA1 = *(const int4*)(kv_ws + (size_t)jqA1*128 + 8*rl);
    kvA2 = *(const int4*)(kv_ws + (size_t)jqA2*128 + 8*rl);
    kvA3 = *(const int4*)(kv_ws + (size_t)jqA3*128 + 8*rl);
    if (n_first + ws < N){
      jrB  = nidx[(n_first+ws)*16 + rl];
      jqB0 = nidx[(n_first+ws)*16 + o*4 + 0];
      jqB1 = nidx[(n_first+ws)*16 + o*4 + 1];
      jqB2 = nidx[(n_first+ws)*16 + o*4 + 2];
      jqB3 = nidx[(n_first+ws)*16 + o*4 + 3];
    }
  }

  for (int n = n_first; n < N; n += 2*ws){
    const int nA = n, nB = n + ws, nC = n + 2*ws, nD = n + 3*ws;
    const bool hasB = (nB < N), hasC = (nC < N), hasD = (nD < N);

    // ---- A's own gathers (covered by A's p-LN, v4-proven placement) ----
    uint2 qA = *(const uint2*)(q_ws + (size_t)nA*64 + 4*rl);
    const float resA = ldf(feat, (size_t)nA*64 + lane, F_feat);
    float relA0 = ldf(points, (size_t)jrA*3 + 0, F_pts) - ldf(points, (size_t)nA*3 + 0, F_pts);
    float relA1 = ldf(points, (size_t)jrA*3 + 1, F_pts) - ldf(points, (size_t)nA*3 + 1, F_pts);
    float relA2 = ldf(points, (size_t)jrA*3 + 2, F_pts) - ldf(points, (size_t)nA*3 + 2, F_pts);

    // ---- issue B's kv NOW (16 VGPR live across chain A; first use ~1500cy) ----
    int4 kvB0={0,0,0,0}, kvB1={0,0,0,0}, kvB2={0,0,0,0}, kvB3={0,0,0,0};
    if (hasB){
      kvB0 = *(const int4*)(kv_ws + (size_t)jqB0*128 + 8*rl);
      kvB1 = *(const int4*)(kv_ws + (size_t)jqB1*128 + 8*rl);
      kvB2 = *(const int4*)(kv_ws + (size_t)jqB2*128 + 8*rl);
      kvB3 = *(const int4*)(kv_ws + (size_t)jqB3*128 + 8*rl);
    }
    __builtin_amdgcn_sched_barrier(0);     // pin: loads above must ISSUE here

    // ---- refill A-role indices for nC (latency hidden under chain A) ----
    int jrA2=0, jqA2_0=0, jqA2_1=0, jqA2_2=0, jqA2_3=0;
    if (hasC){
      jrA2   = nidx[nC*16 + rl];
      jqA2_0 = nidx[nC*16 + o*4 + 0];
      jqA2_1 = nidx[nC*16 + o*4 + 1];
      jqA2_2 = nidx[nC*16 + o*4 + 2];
      jqA2_3 = nidx[nC*16 + o*4 + 3];
    }

    // ---- chain A ----
    point_chain(nA, kvA0, kvA1, kvA2, kvA3, qA, resA, relA0, relA1, relA2,
                wpf, bpC, gpC, bePC, bg1C, ggC, beGC, bg2C, boC,
                xb, yb, wldsL, o, rl, lane, F_feat, out);

    if (hasB){
      // ---- B's own gathers ----
      uint2 qB = *(const uint2*)(q_ws + (size_t)nB*64 + 4*rl);
      const float resB = ldf(feat, (size_t)nB*64 + lane, F_feat);
      float relB0 = ldf(points, (size_t)jrB*3 + 0, F_pts) - ldf(points, (size_t)nB*3 + 0, F_pts);
      float relB1 = ldf(points, (size_t)jrB*3 + 1, F_pts) - ldf(points, (size_t)nB*3 + 1, F_pts);
      float relB2 = ldf(points, (size_t)jrB*3 + 2, F_pts) - ldf(points, (size_t)nB*3 + 2, F_pts);

      // ---- issue next-A kv (for nC), hidden under chain B ----
      int4 kvN0={0,0,0,0}, kvN1={0,0,0,0}, kvN2={0,0,0,0}, kvN3={0,0,0,0};
      if (hasC){
        kvN0 = *(const int4*)(kv_ws + (size_t)jqA2_0*128 + 8*rl);
        kvN1 = *(const int4*)(kv_ws + (size_t)jqA2_1*128 + 8*rl);
        kvN2 = *(const int4*)(kv_ws + (size_t)jqA2_2*128 + 8*rl);
        kvN3 = *(const int4*)(kv_ws + (size_t)jqA2_3*128 + 8*rl);
      }
      __builtin_amdgcn_sched_barrier(0);

      // ---- refill B-role indices for nD ----
      if (hasD){
        jrB  = nidx[nD*16 + rl];
        jqB0 = nidx[nD*16 + o*4 + 0];
        jqB1 = nidx[nD*16 + o*4 + 1];
        jqB2 = nidx[nD*16 + o*4 + 2];
        jqB3 = nidx[nD*16 + o*4 + 3];
      }

      // ---- chain B ----
      point_chain(nB, kvB0, kvB1, kvB2, kvB3, qB, resB, relB0, relB1, relB2,
                  wpf, bpC, gpC, bePC, bg1C, ggC, beGC, bg2C, boC,
                  xb, yb, wldsL, o, rl, lane, F_feat, out);

      // ---- rotate A-role state ----
      kvA0 = kvN0; kvA1 = kvN1; kvA2 = kvN2; kvA3 = kvN3;
      jrA = jrA2; jqA0 = jqA2_0; jqA1 = jqA2_1; jqA2 = jqA2_2; jqA3 = jqA2_3;
    }
  }
}

// ============================================================================
extern "C" void kernel_launch(void* const* d_in, const int* in_sizes, int n_in,
                              void* d_out, int out_size, void* d_ws, size_t ws_size,
                              hipStream_t stream)
{
  const int N = in_sizes[1] / 64;

  unsigned short* q_ws  = (unsigned short*)d_ws;           // N*64 shorts
  unsigned short* kv_ws = q_ws + (size_t)N * 64;           // N*128 shorts (k|v interleaved)
  char* base = (char*)d_ws + (size_t)3 * N * 64 * sizeof(unsigned short);
  int*            flags  = (int*)base;                            // 128 B
  unsigned short* wfrag  = (unsigned short*)(base + 256);         // 49152 B
  unsigned short* wp_bf  = (unsigned short*)(base + 256 + 49152); // 384 B (pad 512)
  float*          biases = (float*)(base + 256 + 49152 + 512);    // 2816 B

  Ptrs ptrs;
  for (int i = 0; i < 21; i++){ ptrs.p[i] = d_in[i]; ptrs.n[i] = in_sizes[i]; }
  PrepPtrs pp;
  pp.w[0] = d_in[3];  pp.w[1] = d_in[5];  pp.w[2] = d_in[7];
  pp.w[3] = d_in[13]; pp.w[4] = d_in[17]; pp.w[5] = d_in[19];
  pp.wp = d_in[9];
  pp.b[0] = d_in[4];  pp.b[1] = d_in[6];  pp.b[2] = d_in[8];  pp.b[3] = d_in[10];
  pp.b[4] = d_in[11]; pp.b[5] = d_in[12]; pp.b[6] = d_in[14]; pp.b[7] = d_in[15];
  pp.b[8] = d_in[16]; pp.b[9] = d_in[18]; pp.b[10] = d_in[20];

  detect_kernel<<<6, 256, 0, stream>>>(ptrs, flags);
  prep_kernel<<<32, 256, 0, stream>>>(pp, flags, wfrag, wp_bf, biases);
  qkv_kernel<<<512, 256, 0, stream>>>(d_in[1], wfrag, biases, q_ws, kv_ws, flags, N);
  pt_kernel<<<2048, 256, 0, stream>>>(d_in[0], d_in[1], (const int*)d_in[2], q_ws, kv_ws,
                                      wfrag, wp_bf, biases, flags, d_out, N);
}